// Round 1
// baseline (739.568 us; speedup 1.0000x reference)
//
#include <hip/hip_runtime.h>
#include <cmath>

// Complete binary tree, level order, levels 0..20. Leaves = level 20.
#define N_NODES_C   ((1 << 21) - 1)   // 2097151
#define N_LEAVES_C  (1 << 20)         // 1048576
#define LEAF_START  (N_LEAVES_C - 1)  // 1048575
#define NFEAT       64

__device__ __forceinline__ float score_fn(float dot, float bias) {
    return 1.0f + tanhf(dot + bias) * 0.1f;  // 1/TANH_SCALAR
}

// 16-lane-group dot product: lane q holds features[4q..4q+3] . W[4q..4q+3];
// butterfly over the 16-lane group (xor masks stay inside the group).
__device__ __forceinline__ float dot16(const float4 f, const float4 w) {
    float v = f.x * w.x + f.y * w.y + f.z * w.z + f.w * w.w;
    v += __shfl_xor(v, 1);
    v += __shfl_xor(v, 2);
    v += __shfl_xor(v, 4);
    v += __shfl_xor(v, 8);
    return v;
}

// One block = 512-leaf subtree. Computes its own scores from features (no
// scores workspace), reduces levels 20 -> 11 in LDS, writes out[] for all
// nodes it owns (leaves, levels 19..12 internals, and its level-11 root).
// 2048 blocks x 256 thr = 8 blocks/CU -> full 32-wave occupancy, streaming.
__global__ __launch_bounds__(256) void tree_reduce_kernel(
        const float* __restrict__ features,
        const float* __restrict__ leaf_energy,
        const float* __restrict__ W,
        const float* __restrict__ b,
        float* __restrict__ out) {
    // sc: scores of internal nodes, levels 19..12, stored at offset 512-2m
    // (m = nodes this block owns at that level): 256,128,...,2 -> 510 slots.
    __shared__ float sc[512];
    __shared__ float buf[2][512];   // ping-pong contributions
    const int tid = threadIdx.x;
    const int q   = tid & 15;        // lane within 16-group
    const int grp = tid >> 4;        // 0..15
    const int blk = blockIdx.x;      // 0..2047
    const float4 w4 = ((const float4*)W)[q];
    const float bias = b[0];
    const int l0 = blk << 9;         // first leaf (local index) of this block

    // (1) coalesced leaf-energy copy to out (energy of a leaf = its input).
    for (int i = tid; i < 512; i += 256)
        out[LEAF_START + l0 + i] = leaf_energy[l0 + i];

    // (2) precompute internal scores (levels 19..12) into LDS. No barriers
    // between levels: all loads independent -> fully pipelined.
    for (int pd = 19; pd >= 12; --pd) {
        const int m = 1 << (pd - 11);
        const int gbase = ((1 << pd) - 1) + blk * m;
        const int off = 512 - 2 * m;
        for (int j = grp; j < m; j += 16) {
            const float4 f = ((const float4*)(features + (size_t)(gbase + j) * NFEAT))[q];
            const float v = dot16(f, w4);
            if (q == 0) sc[off + j] = score_fn(v, bias);
        }
    }

    // (3) leaf contributions: score(leaf) * energy(leaf) into buf[0].
    for (int j = grp; j < 512; j += 16) {
        const size_t g = (size_t)(LEAF_START + l0 + j);
        const float4 f = ((const float4*)(features + g * NFEAT))[q];
        const float v = dot16(f, w4);
        if (q == 0) buf[0][j] = score_fn(v, bias) * leaf_energy[l0 + j];
    }

    // (4) reduce levels 19..11 purely in LDS; coalesced out stores.
    int p = 0;
    for (int pd = 19; pd >= 11; --pd) {
        const int m = 1 << (pd - 11);
        __syncthreads();
        const int gbase = ((1 << pd) - 1) + blk * m;
        for (int j = tid; j < m; j += 256) {
            const float val = buf[p][2 * j] + buf[p][2 * j + 1];  // 2-way = free
            out[gbase + j] = val;
            if (pd > 11)
                buf[1 - p][j] = sc[(512 - 2 * m) + j] * val;
        }
        p ^= 1;
    }
}

// One block finishes levels 10..0 from the 2048 level-11 energies in
// out[2047..4095). All 4095 top-of-tree scores are precomputed into LDS
// BEFORE the reduction -> the dependent level chain has zero global latency.
__global__ __launch_bounds__(1024) void top_kernel(
        const float* __restrict__ features,
        const float* __restrict__ W,
        const float* __restrict__ b,
        float* __restrict__ out) {
    __shared__ float slds[4096];     // scores of nodes 0..4094 ([0] unused)
    __shared__ float buf[2][2048];
    const int tid = threadIdx.x;
    const int q   = tid & 15;
    const int grp = tid >> 4;        // 0..63
    const float4 w4 = ((const float4*)W)[q];
    const float bias = b[0];

    // scores for nodes 0..4094 (64 groups x 64 iterations, pipelined loads)
    for (int j = grp; j < 4095; j += 64) {
        const float4 f = ((const float4*)(features + (size_t)j * NFEAT))[q];
        const float v = dot16(f, w4);
        if (q == 0) slds[j] = score_fn(v, bias);
    }
    __syncthreads();

    // level-11 contributions from energies written by tree_reduce_kernel
    for (int i = tid; i < 2048; i += 1024)
        buf[0][i] = slds[2047 + i] * out[2047 + i];

    int p = 0;
    for (int pd = 10; pd >= 0; --pd) {
        const int m = 1 << pd;
        __syncthreads();
        const int base = m - 1;
        for (int j = tid; j < m; j += 1024) {
            const float val = buf[p][2 * j] + buf[p][2 * j + 1];
            out[base + j] = val;
            if (pd > 0)
                buf[1 - p][j] = slds[base + j] * val;
        }
        p ^= 1;
    }
}

extern "C" void kernel_launch(void* const* d_in, const int* in_sizes, int n_in,
                              void* d_out, int out_size, void* d_ws, size_t ws_size,
                              hipStream_t stream) {
    (void)in_sizes; (void)n_in; (void)out_size; (void)d_ws; (void)ws_size;
    const float* features    = (const float*)d_in[0];  // [N_NODES, 64]
    const float* leaf_energy = (const float*)d_in[1];  // [N_LEAVES]
    const float* W           = (const float*)d_in[2];  // [64]
    const float* b           = (const float*)d_in[3];  // [1]
    float* out = (float*)d_out;                        // [N_NODES]

    tree_reduce_kernel<<<2048, 256, 0, stream>>>(features, leaf_energy, W, b, out);
    top_kernel<<<1, 1024, 0, stream>>>(features, W, b, out);
}

// Round 2
// 701.076 us; speedup vs baseline: 1.0549x; 1.0549x over previous
//
#include <hip/hip_runtime.h>
#include <cmath>

// Complete binary tree, level order, levels 0..20. Leaves = level 20.
#define N_NODES_C   ((1 << 21) - 1)   // 2097151
#define N_LEAVES_C  (1 << 20)         // 1048576
#define LEAF_START  (N_LEAVES_C - 1)  // 1048575
#define NFEAT       64

__device__ __forceinline__ float score_fn(float dot, float bias) {
    return 1.0f + tanhf(dot + bias) * 0.1f;  // 1/TANH_SCALAR
}

// K1: streaming pass over ALL nodes' features (the only kernel touching the
// 537 MB features array). 8 lanes/node, 32 B/lane -> 8 nodes per wave-iter,
// 3-shuffle reduce, one masked tanh per 8 nodes.
//   ws[node] = score                      (internal nodes)
//   ws[node] = score * leaf_energy       (leaves)  + out[leaf] = energy
__global__ __launch_bounds__(256) void score_stream_kernel(
        const float* __restrict__ features,
        const float* __restrict__ leaf_energy,
        const float* __restrict__ W,
        const float* __restrict__ b,
        float* __restrict__ ws,
        float* __restrict__ out) {
    const int q = threadIdx.x & 7;                 // lane within 8-group
    const float4 wl = ((const float4*)W)[q];       // W[4q .. 4q+3]
    const float4 wh = ((const float4*)W)[q + 8];   // W[4q+32 .. 4q+35]
    const float bias = b[0];
    const int g0 = (blockIdx.x * 256 + threadIdx.x) >> 3;   // node id
    const int gstride = (gridDim.x * 256) >> 3;
    for (int node = g0; node < N_NODES_C; node += gstride) {
        const float4* fp = (const float4*)(features + (size_t)node * NFEAT);
        const float4 a = fp[q];        // first 128 B of the row (8 lanes)
        const float4 c = fp[q + 8];    // second 128 B
        float v = a.x * wl.x + a.y * wl.y + a.z * wl.z + a.w * wl.w
                + c.x * wh.x + c.y * wh.y + c.z * wh.z + c.w * wh.w;
        v += __shfl_xor(v, 1);
        v += __shfl_xor(v, 2);
        v += __shfl_xor(v, 4);
        if (q == 0) {
            const float s = score_fn(v, bias);
            if (node >= LEAF_START) {
                const float e = leaf_energy[node - LEAF_START];
                ws[node] = s * e;      // leaf contribution, ready for K2
                out[node] = e;         // leaf energy is part of the output
            } else {
                ws[node] = s;
            }
        }
    }
}

// K2: 1024 blocks, each owns 1024 leaves; reduces levels 20 -> 10 in LDS.
// All internal scores (levels 19..11) preloaded BEFORE the barrier chain,
// so the dependent per-level loop is pure LDS. Writes out[] levels 19..10.
__global__ __launch_bounds__(256) void mid_reduce_kernel(
        const float* __restrict__ ws,
        float* __restrict__ out) {
    __shared__ float sc[1024];       // scores, level pd at offset 1024-2m
    __shared__ float buf[2][1024];   // ping-pong contributions
    const int tid = threadIdx.x;
    const int blk = blockIdx.x;      // 0..1023

    // contributions of this block's 1024 leaves (contiguous, coalesced)
    const int lbase = LEAF_START + (blk << 10);
    for (int i = tid; i < 1024; i += 256)
        buf[0][i] = ws[lbase + i];

    // preload internal scores for levels 19..11 (independent loads, no chain)
    for (int pd = 19; pd >= 11; --pd) {
        const int m = 1 << (pd - 10);            // 512 .. 2
        const int gbase = ((1 << pd) - 1) + blk * m;
        const int off = 1024 - 2 * m;
        for (int j = tid; j < m; j += 256)
            sc[off + j] = ws[gbase + j];
    }

    int p = 0;
    for (int pd = 19; pd >= 10; --pd) {
        const int m = 1 << (pd - 10);            // 512 .. 1
        __syncthreads();
        const int gbase = ((1 << pd) - 1) + blk * m;
        for (int j = tid; j < m; j += 256) {
            const float val = buf[p][2 * j] + buf[p][2 * j + 1]; // 2-way = free
            out[gbase + j] = val;
            if (pd > 10)
                buf[1 - p][j] = sc[(1024 - 2 * m) + j] * val;
        }
        p ^= 1;
    }
}

// K3: one block finishes levels 10..0 from the 1024 level-10 energies.
// Consumes only precomputed scores (ws[0..2046]) -- NO feature traffic.
__global__ __launch_bounds__(1024) void top_reduce_kernel(
        const float* __restrict__ ws,
        float* __restrict__ out) {
    __shared__ float sc[2048];       // scores of nodes 0..2046
    __shared__ float buf[2][1024];
    const int tid = threadIdx.x;
    for (int i = tid; i < 2047; i += 1024)
        sc[i] = ws[i];
    // level-10 contributions: energies written by K2 at out[1023..2047)
    buf[0][tid] = out[1023 + tid];   // energy first; scale after sc is synced
    __syncthreads();
    buf[0][tid] = sc[1023 + tid] * buf[0][tid];

    int p = 0;
    for (int pd = 9; pd >= 0; --pd) {
        const int m = 1 << pd;
        __syncthreads();
        const int base = m - 1;
        for (int j = tid; j < m; j += 1024) {
            const float val = buf[p][2 * j] + buf[p][2 * j + 1];
            out[base + j] = val;
            if (pd > 0)
                buf[1 - p][j] = sc[base + j] * val;
        }
        p ^= 1;
    }
}

extern "C" void kernel_launch(void* const* d_in, const int* in_sizes, int n_in,
                              void* d_out, int out_size, void* d_ws, size_t ws_size,
                              hipStream_t stream) {
    (void)in_sizes; (void)n_in; (void)out_size; (void)ws_size;
    const float* features    = (const float*)d_in[0];  // [N_NODES, 64]
    const float* leaf_energy = (const float*)d_in[1];  // [N_LEAVES]
    const float* W           = (const float*)d_in[2];  // [64]
    const float* b           = (const float*)d_in[3];  // [1]
    float* out = (float*)d_out;                        // [N_NODES]
    float* ws  = (float*)d_ws;                         // N_NODES floats (8.4 MB)

    // 8192 blocks x 32 node-groups = 262144 groups -> 8 grid-stride iters.
    score_stream_kernel<<<8192, 256, 0, stream>>>(features, leaf_energy, W, b, ws, out);
    mid_reduce_kernel<<<1024, 256, 0, stream>>>(ws, out);
    top_reduce_kernel<<<1, 1024, 0, stream>>>(ws, out);
}

// Round 3
// 666.574 us; speedup vs baseline: 1.1095x; 1.0518x over previous
//
#include <hip/hip_runtime.h>
#include <cmath>

// Complete binary tree, level order, levels 0..20. Leaves = level 20.
#define N_NODES_C   ((1 << 21) - 1)   // 2097151
#define N_LEAVES_C  (1 << 20)         // 1048576
#define LEAF_START  (N_LEAVES_C - 1)  // 1048575
#define NFEAT       64

typedef float f32x4 __attribute__((ext_vector_type(4)));

__device__ __forceinline__ float score_fn(float dot, float bias) {
    return 1.0f + tanhf(dot + bias) * 0.1f;  // 1/TANH_SCALAR
}

// K1: the ONLY kernel touching the 537 MB features array. Branch-free:
// ws[node] = score(node) for every node (leaves included). 8 lanes/node,
// 32 B/lane via two nontemporal float4 loads (features have zero reuse ->
// evict-first, keeps L2 clean for the ws lines K2 re-reads).
__global__ __launch_bounds__(256) void score_stream_kernel(
        const float* __restrict__ features,
        const float* __restrict__ W,
        const float* __restrict__ b,
        float* __restrict__ ws) {
    const int q = threadIdx.x & 7;                 // lane within 8-group
    const f32x4 wl = ((const f32x4*)W)[q];         // W[4q .. 4q+3]
    const f32x4 wh = ((const f32x4*)W)[q + 8];     // W[4q+32 .. 4q+35]
    const float bias = b[0];
    const int g0 = (blockIdx.x * 256 + threadIdx.x) >> 3;   // node id
    const int gstride = (gridDim.x * 256) >> 3;             // 262144
    for (int node = g0; node < N_NODES_C; node += gstride) {
        const f32x4* fp = (const f32x4*)(features + (size_t)node * NFEAT);
        const f32x4 a = __builtin_nontemporal_load(fp + q);      // bytes [0,128)
        const f32x4 c = __builtin_nontemporal_load(fp + q + 8);  // bytes [128,256)
        float v = a.x * wl.x + a.y * wl.y + a.z * wl.z + a.w * wl.w
                + c.x * wh.x + c.y * wh.y + c.z * wh.z + c.w * wh.w;
        v += __shfl_xor(v, 1);
        v += __shfl_xor(v, 2);
        v += __shfl_xor(v, 4);
        if (q == 0) ws[node] = score_fn(v, bias);
    }
}

// K2: 2048 blocks (8/CU, fully resident), each owns 512 leaves.
// Reads leaf scores + leaf energies, writes out[leaf]=e, reduces levels
// 20 -> 11 with all internal scores preloaded BEFORE the barrier chain.
__global__ __launch_bounds__(256) void mid_reduce_kernel(
        const float* __restrict__ ws,
        const float* __restrict__ leaf_energy,
        float* __restrict__ out) {
    __shared__ float sc[512];        // scores of levels 19..12: offset 512-2m
    __shared__ float buf[2][512];    // ping-pong contributions
    const int tid = threadIdx.x;
    const int blk = blockIdx.x;      // 0..2047

    // leaves: out[leaf] = e, buf[0] = score*e (coalesced 2 KB streams)
    const int l0 = blk << 9;
    for (int i = tid; i < 512; i += 256) {
        const float e = leaf_energy[l0 + i];
        const float s = ws[LEAF_START + l0 + i];
        out[LEAF_START + l0 + i] = e;
        buf[0][i] = s * e;
    }

    // preload internal scores, levels 19..12 (independent loads, no chain)
    for (int pd = 19; pd >= 12; --pd) {
        const int m = 1 << (pd - 11);            // 256 .. 2
        const int gbase = ((1 << pd) - 1) + blk * m;
        const int off = 512 - 2 * m;
        for (int j = tid; j < m; j += 256)
            sc[off + j] = ws[gbase + j];
    }

    // produce levels 19 .. 11 (pd = level being produced)
    int p = 0;
    for (int pd = 19; pd >= 11; --pd) {
        const int m = 1 << (pd - 11);            // 256 .. 1
        __syncthreads();
        const int gbase = ((1 << pd) - 1) + blk * m;
        for (int j = tid; j < m; j += 256) {
            const float val = buf[p][2 * j] + buf[p][2 * j + 1]; // 2-way = free
            out[gbase + j] = val;
            if (pd > 11)
                buf[1 - p][j] = sc[(512 - 2 * m) + j] * val;
        }
        p ^= 1;
    }
}

// K3: one block finishes levels 10..0 from the 2048 level-11 energies.
// Consumes only precomputed scores (ws[0..4094]) -- NO feature traffic;
// the whole dependent level chain is pure LDS.
__global__ __launch_bounds__(1024) void top_reduce_kernel(
        const float* __restrict__ ws,
        float* __restrict__ out) {
    __shared__ float sc[4095];       // scores of nodes 0..4094
    __shared__ float buf[2][2048];
    const int tid = threadIdx.x;
    // level-11 energies (out[2047..4095), written by K2) -> registers
    const float e0 = out[2047 + tid];
    const float e1 = out[3071 + tid];
    for (int i = tid; i < 4095; i += 1024)
        sc[i] = ws[i];
    __syncthreads();
    buf[0][tid]        = sc[2047 + tid] * e0;
    buf[0][tid + 1024] = sc[3071 + tid] * e1;

    int p = 0;
    for (int pd = 10; pd >= 0; --pd) {
        const int m = 1 << pd;       // 1024 .. 1
        __syncthreads();
        const int base = m - 1;
        for (int j = tid; j < m; j += 1024) {
            const float val = buf[p][2 * j] + buf[p][2 * j + 1];
            out[base + j] = val;
            if (pd > 0)
                buf[1 - p][j] = sc[base + j] * val;
        }
        p ^= 1;
    }
}

extern "C" void kernel_launch(void* const* d_in, const int* in_sizes, int n_in,
                              void* d_out, int out_size, void* d_ws, size_t ws_size,
                              hipStream_t stream) {
    (void)in_sizes; (void)n_in; (void)out_size; (void)ws_size;
    const float* features    = (const float*)d_in[0];  // [N_NODES, 64]
    const float* leaf_energy = (const float*)d_in[1];  // [N_LEAVES]
    const float* W           = (const float*)d_in[2];  // [64]
    const float* b           = (const float*)d_in[3];  // [1]
    float* out = (float*)d_out;                        // [N_NODES]
    float* ws  = (float*)d_ws;                         // N_NODES floats (8.4 MB)

    // 8192 blocks x 32 groups = 262144 groups -> 8 grid-stride iterations.
    score_stream_kernel<<<8192, 256, 0, stream>>>(features, W, b, ws);
    mid_reduce_kernel<<<2048, 256, 0, stream>>>(ws, leaf_energy, out);
    top_reduce_kernel<<<1, 1024, 0, stream>>>(ws, out);
}